// Round 17
// baseline (203.046 us; speedup 1.0000x reference)
//
#include <hip/hip_runtime.h>
#include <hip/hip_bf16.h>
#include <hip/hip_cooperative_groups.h>

namespace cg = cooperative_groups;

#define DIM   128
#define BM    64
#define WIN_NODES 25088             // nodes per LDS window
#define WIN_PAIRS (WIN_NODES / 2)   // 12544 uints = 50176 B LDS

typedef short  bf16x8 __attribute__((ext_vector_type(8)));
typedef float  f32x4  __attribute__((ext_vector_type(4)));

__device__ __forceinline__ ushort f2bf(float f) {   // round-to-nearest-even
    uint u = __float_as_uint(f);
    return (ushort)((u + 0x7FFFu + ((u >> 16) & 1u)) >> 16);
}

// ---------------------------------------------------------------------------
// K1 (cooperative): hist -> prefix+WT -> scan -> fill, grid.sync between
// phases.  Replaces 4 launches (and their gaps) with 1.
//  P1: one-pass-per-block chunk histograms (r13 form), 50 KB LDS window x2.
//  P2: per-node chunk-prefix (D, in place) + deg_in; S totals -> norm_src;
//      tail ids convert W -> WT bf16 transposed.
//  P3: redundant-prefix exclusive scan deg_in -> offs (r13 scan4 body).
//  P4: streaming scatter fill (grid-stride, no atomics).
// ---------------------------------------------------------------------------
__global__ __launch_bounds__(1024, 8) void preproc_kernel(
    const int* __restrict__ src, const int* __restrict__ dst,
    uint* __restrict__ histD, uint* __restrict__ histS,
    int* __restrict__ rank, int* __restrict__ deg_in, int* __restrict__ offs,
    float* __restrict__ norm_src, const float* __restrict__ W,
    ushort* __restrict__ WT, int* __restrict__ esrc,
    int n_edges, int n_nodes, int pairs_row, int nwin, int chunk, int C) {
    cg::grid_group grid = cg::this_grid();
    __shared__ uint hh[WIN_PAIRS];
    __shared__ int  w1[16], w2[16];
    const int tid = threadIdx.x;
    const int b   = blockIdx.x;
    const int npad = 2 * pairs_row;

    // ---- P1: hist ----
    for (int blk = b; blk < 2 * C; blk += gridDim.x) {
        const bool isD = blk < C;
        const int  c   = isD ? blk : blk - C;
        const int  beg = c * chunk;
        const int  end = min(beg + chunk, n_edges);
        const int* key = isD ? dst : src;
        uint* outb     = isD ? histD : histS;
        for (int half = 0; half < nwin; ++half) {
            const int plo    = half * WIN_PAIRS;
            const int wpairs = min(WIN_PAIRS, pairs_row - plo);
            const int wnodes = wpairs * 2;
            const int lo     = plo * 2;
            for (int j = tid; j < wpairs; j += 1024) hh[j] = 0;
            __syncthreads();
            for (int e = beg + tid; e < end; e += 1024) {
                int r = key[e] - lo;
                if ((unsigned)r < (unsigned)wnodes) {
                    uint old = atomicAdd(&hh[r >> 1], 1u << ((r & 1) * 16));
                    if (isD)
                        rank[e] = (r & 1) ? (int)(old >> 16) : (int)(old & 0xFFFFu);
                }
            }
            __syncthreads();
            uint* row = outb + (size_t)c * pairs_row + plo;
            for (int j = tid; j < wpairs; j += 1024) row[j] = hh[j];
            __syncthreads();
        }
    }
    grid.sync();

    // ---- P2: prefix + WT ----
    {
        const int total = 2 * pairs_row + DIM * DIM;
        const int stride = gridDim.x * 1024;
        for (int id = b * 1024 + tid; id < total; id += stride) {
            if (id < pairs_row) {
                uint* col = histD + id;
                uint run0 = 0, run1 = 0;
                for (int c = 0; c < C; ++c) {
                    uint v = col[(size_t)c * pairs_row];
                    col[(size_t)c * pairs_row] = run0 | (run1 << 16);
                    run0 += v & 0xFFFFu;
                    run1 += v >> 16;
                }
                deg_in[2 * id]     = (int)run0;
                deg_in[2 * id + 1] = (int)run1;
            } else if (id < 2 * pairs_row) {
                int j = id - pairs_row;
                const uint* col = histS + j;
                uint run0 = 0, run1 = 0;
                for (int c = 0; c < C; ++c) {
                    uint v = col[(size_t)c * pairs_row];
                    run0 += v & 0xFFFFu;
                    run1 += v >> 16;
                }
                int n0 = 2 * j, n1 = 2 * j + 1;
                if (n0 < n_nodes) norm_src[n0] = rsqrtf(fmaxf((float)run0, 1.0f));
                if (n1 < n_nodes) norm_src[n1] = rsqrtf(fmaxf((float)run1, 1.0f));
            } else {
                int idx = id - 2 * pairs_row;
                int k = idx >> 7, cc = idx & 127;
                WT[cc * DIM + k] = f2bf(W[idx]);
            }
        }
    }
    grid.sync();

    // ---- P3: scan (r13 scan4 body; blocks with base < npad active) ----
    for (int base = b * 4096; base < npad; base += gridDim.x * 4096) {
        const int lane = tid & 63, wid = tid >> 6;
        const int n = npad;
        int part = 0;
        for (int i = base ? tid : n; i < base; i += 1024) part += deg_in[i];
#pragma unroll
        for (int o = 32; o; o >>= 1) part += __shfl_xor(part, o);
        if (lane == 0) w1[wid] = part;
        __syncthreads();
        int prefix = 0;
#pragma unroll
        for (int k = 0; k < 16; ++k) prefix += w1[k];

        int i0 = base + tid * 4;
        int e0 = (i0 + 0 < n) ? deg_in[i0 + 0] : 0;
        int e1 = (i0 + 1 < n) ? deg_in[i0 + 1] : 0;
        int e2 = (i0 + 2 < n) ? deg_in[i0 + 2] : 0;
        int e3 = (i0 + 3 < n) ? deg_in[i0 + 3] : 0;
        int s  = e0 + e1 + e2 + e3;
        int sc = s;
#pragma unroll
        for (int o = 1; o < 64; o <<= 1) {
            int t = __shfl_up(sc, o);
            if (lane >= o) sc += t;
        }
        if (lane == 63) w2[wid] = sc;
        __syncthreads();
        int wpre = 0;
        for (int k = 0; k < wid; ++k) wpre += w2[k];
        int excl = prefix + wpre + sc - s;
        int o1 = excl + e0, o2 = o1 + e1, o3 = o2 + e2, o4 = o3 + e3;
        if (i0 + 0 < n) offs[i0 + 1] = o1;
        if (i0 + 1 < n) offs[i0 + 2] = o2;
        if (i0 + 2 < n) offs[i0 + 3] = o3;
        if (i0 + 3 < n) offs[i0 + 4] = o4;
        if (base == 0 && tid == 0) offs[0] = 0;
    }
    grid.sync();

    // ---- P4: fill (grid-stride) ----
    {
        const int stride = gridDim.x * 1024;
        for (int e = b * 1024 + tid; e < n_edges; e += stride) {
            int t = dst[e];
            int c = e / chunk;
            uint pf = histD[(size_t)c * pairs_row + (t >> 1)];
            int pref = (t & 1) ? (int)(pf >> 16) : (int)(pf & 0xFFFFu);
            esrc[offs[t] + pref + rank[e]] = src[e];
        }
    }
}

// ---------------------------------------------------------------------------
// K2: MFMA transform GEMM.  h[r,:] = bf16( norm_src[r] * (x[r,:] @ W) ).
// (r10/r16 form, verified)
// ---------------------------------------------------------------------------
__global__ __launch_bounds__(256, 4) void gemmx_kernel(const float* __restrict__ x,
                                                       const ushort* __restrict__ WT,
                                                       const float* __restrict__ norm_src,
                                                       ushort* __restrict__ h,
                                                       int n_nodes) {
    __shared__ ushort WsT[DIM * DIM];   // 32 KB, swizzled [c][k]
    const int tid = threadIdx.x;

    {
        const uint4* wsrc = reinterpret_cast<const uint4*>(WT);
#pragma unroll
        for (int i = 0; i < 8; ++i) {
            int linear = tid + i * 256;           // 0..2047 16B-units
            uint4 v = wsrc[linear];
            int byte = linear * 16;
            int c = byte >> 8;
            int swz = byte ^ ((c & 7) << 4);
            *reinterpret_cast<uint4*>(reinterpret_cast<char*>(WsT) + swz) = v;
        }
    }
    __syncthreads();

    const int lane = tid & 63;
    const int w    = tid >> 6;
    const int r0   = blockIdx.x * BM;
    const int rowm = r0 + w * 16 + (lane & 15);
    const int rowc = min(rowm, n_nodes - 1);
    const float4* X4 = reinterpret_cast<const float4*>(x);

    f32x4 acc[8];
#pragma unroll
    for (int t = 0; t < 8; ++t) acc[t] = (f32x4){0.f, 0.f, 0.f, 0.f};

#pragma unroll
    for (int s = 0; s < 4; ++s) {
        int idx = rowc * 32 + s * 8 + (lane >> 4) * 2;
        float4 v0 = X4[idx];
        float4 v1 = X4[idx + 1];
        bf16x8 a;
        a[0] = (short)f2bf(v0.x); a[1] = (short)f2bf(v0.y);
        a[2] = (short)f2bf(v0.z); a[3] = (short)f2bf(v0.w);
        a[4] = (short)f2bf(v1.x); a[5] = (short)f2bf(v1.y);
        a[6] = (short)f2bf(v1.z); a[7] = (short)f2bf(v1.w);
#pragma unroll
        for (int t = 0; t < 8; ++t) {
            int c   = t * 16 + (lane & 15);
            int ofs = c * 256 + s * 64 + (lane >> 4) * 16;
            ofs ^= (c & 7) << 4;
            bf16x8 bfr = *reinterpret_cast<const bf16x8*>(
                reinterpret_cast<const char*>(WsT) + ofs);
            acc[t] = __builtin_amdgcn_mfma_f32_16x16x32_bf16(a, bfr, acc[t], 0, 0, 0);
        }
    }

#pragma unroll
    for (int i = 0; i < 4; ++i) {
        int row = r0 + w * 16 + (lane >> 4) * 4 + i;
        if (row < n_nodes) {
            float ns = norm_src[row];
            ushort* hp = h + (size_t)row * DIM + (lane & 15);
#pragma unroll
            for (int t = 0; t < 8; ++t)
                hp[t * 16] = f2bf(acc[t][i] * ns);
        }
    }
}

// ---------------------------------------------------------------------------
// K3: gather (r10/r13/r16 proven form).  One wave per node, 1 uint (2 bf16)
// per lane, x8 unroll.  out[t,:] = nd(t) * sum h[src_e,:] + b.
// ---------------------------------------------------------------------------
__global__ __launch_bounds__(256) void gather_kernel(const ushort* __restrict__ h,
                                                     const int* __restrict__ esrc,
                                                     const int* __restrict__ offs,
                                                     const float* __restrict__ bg,
                                                     float* __restrict__ out,
                                                     int n_nodes) {
    int node = blockIdx.x * 4 + (threadIdx.x >> 6);
    if (node >= n_nodes) return;
    int lane = threadIdx.x & 63;
    int j = offs[node], end = offs[node + 1];
    int deg = end - j;
    const uint* hp = reinterpret_cast<const uint*>(h);
    float ax[8], ay[8];
#pragma unroll
    for (int q = 0; q < 8; ++q) { ax[q] = 0.f; ay[q] = 0.f; }
    for (; j + 7 < end; j += 8) {
        int   si[8];
        uint  u[8];
#pragma unroll
        for (int q = 0; q < 8; ++q) si[q] = esrc[j + q];
#pragma unroll
        for (int q = 0; q < 8; ++q) u[q] = hp[(size_t)si[q] * 64 + lane];
#pragma unroll
        for (int q = 0; q < 8; ++q) {
            ax[q] += __uint_as_float(u[q] << 16);
            ay[q] += __uint_as_float(u[q] & 0xFFFF0000u);
        }
    }
    for (; j + 3 < end; j += 4) {
        int  si[4];
        uint u[4];
#pragma unroll
        for (int q = 0; q < 4; ++q) si[q] = esrc[j + q];
#pragma unroll
        for (int q = 0; q < 4; ++q) u[q] = hp[(size_t)si[q] * 64 + lane];
#pragma unroll
        for (int q = 0; q < 4; ++q) {
            ax[q] += __uint_as_float(u[q] << 16);
            ay[q] += __uint_as_float(u[q] & 0xFFFF0000u);
        }
    }
    for (; j < end; ++j) {
        uint u = hp[(size_t)esrc[j] * 64 + lane];
        ax[0] += __uint_as_float(u << 16);
        ay[0] += __uint_as_float(u & 0xFFFF0000u);
    }
    float sx = ((ax[0] + ax[1]) + (ax[2] + ax[3])) + ((ax[4] + ax[5]) + (ax[6] + ax[7]));
    float sy = ((ay[0] + ay[1]) + (ay[2] + ay[3])) + ((ay[4] + ay[5]) + (ay[6] + ay[7]));
    float nd = rsqrtf(fmaxf((float)deg, 1.0f));
    float2 bv = reinterpret_cast<const float2*>(bg)[lane];
    float2 r;
    r.x = sx * nd + bv.x;
    r.y = sy * nd + bv.y;
    reinterpret_cast<float2*>(out)[(size_t)node * 64 + lane] = r;
}

extern "C" void kernel_launch(void* const* d_in, const int* in_sizes, int n_in,
                              void* d_out, int out_size, void* d_ws, size_t ws_size,
                              hipStream_t stream) {
    const float* x   = (const float*)d_in[0];
    const int*   src = (const int*)d_in[1];
    const int*   dst = (const int*)d_in[2];
    const float* W   = (const float*)d_in[3];
    const float* b   = (const float*)d_in[4];
    float* out = (float*)d_out;

    const int n_nodes = in_sizes[0] / DIM;
    const int n_edges = in_sizes[1];

    const int nwin      = (n_nodes + WIN_NODES - 1) / WIN_NODES;
    const int npad      = nwin * WIN_NODES;
    const int pairs_row = npad / 2;

    auto need = [&](int C) -> size_t {
        return 2ull * n_nodes * DIM + 2ull * DIM * DIM +
               4ull * ((size_t)2 * npad + 1 + n_nodes +
                       2ull * C * pairs_row + 2ull * n_edges);
    };
    int C = 64;                              // per pass (D and S)
    if (ws_size < need(64)) C = 32;
    if (ws_size < need(32)) C = 16;
    const int chunk = (n_edges + C - 1) / C; // <= 50000 < 65536: u16-safe

    // ws layout (all fully overwritten -> NO memset needed):
    // [h N*DIM bf16][WT 128*128 bf16][deg_in npad][offs npad+1][norm_src N]
    // [histD C*pairs][histS C*pairs][rank E][esrc E]
    ushort* h        = (ushort*)d_ws;
    ushort* WT       = h + (size_t)n_nodes * DIM;
    int*    deg_in   = (int*)(WT + DIM * DIM);
    int*    offs     = deg_in + npad;
    float*  norm_src = (float*)(offs + npad + 1);
    uint*   histD    = (uint*)(norm_src + n_nodes);
    uint*   histS    = histD + (size_t)C * pairs_row;
    int*    rank     = (int*)(histS + (size_t)C * pairs_row);
    int*    esrc     = rank + n_edges;

    // Cooperative grid: clamp to co-residency (host-side query, capture-safe).
    int occ = 0;
    hipOccupancyMaxActiveBlocksPerMultiprocessor(&occ, preproc_kernel, 1024, 0);
    if (occ < 1) occ = 1;
    int CB = occ * 256;
    if (CB > 512) CB = 512;

    int ne = n_edges, nn = n_nodes, pr = pairs_row, nw = nwin, ch = chunk, cc = C;
    void* kargs[] = {
        (void*)&x /*placeholder fix below*/
    };
    // build args properly (order must match preproc_kernel params)
    void* args[17];
    args[0]  = (void*)&src;      args[1]  = (void*)&dst;
    args[2]  = (void*)&histD;    args[3]  = (void*)&histS;
    args[4]  = (void*)&rank;     args[5]  = (void*)&deg_in;
    args[6]  = (void*)&offs;     args[7]  = (void*)&norm_src;
    args[8]  = (void*)&W;        args[9]  = (void*)&WT;
    args[10] = (void*)&esrc;     args[11] = (void*)&ne;
    args[12] = (void*)&nn;       args[13] = (void*)&pr;
    args[14] = (void*)&nw;       args[15] = (void*)&ch;
    args[16] = (void*)&cc;
    (void)kargs;

    hipLaunchCooperativeKernel((const void*)preproc_kernel, dim3(CB), dim3(1024),
                               args, 0, stream);
    gemmx_kernel<<<(n_nodes + BM - 1) / BM, 256, 0, stream>>>(
        x, WT, norm_src, h, n_nodes);
    gather_kernel<<<(n_nodes + 3) / 4, 256, 0, stream>>>(
        h, esrc, offs, b, out, n_nodes);
}